// Round 22
// baseline (94.241 us; speedup 1.0000x reference)
//
#include <hip/hip_runtime.h>
#include <hip/hip_bf16.h>

typedef __bf16 bf16;
typedef __attribute__((ext_vector_type(2))) __bf16 bf16x2;
typedef __attribute__((ext_vector_type(4))) __bf16 bf16x4;
typedef __attribute__((ext_vector_type(8))) __bf16 bf16x8;
typedef __attribute__((ext_vector_type(4))) float f32x4;

#define NB 4
#define NS 1024
#define NE 1024
#define NH 16
#define ND 64
#define NROT 32
#define NM (NB*NS)   // 4096 rows

// ---- async global->LDS, 16B per lane, wave-uniform LDS base ----
__device__ __forceinline__ void gload_lds16(const bf16* g, void* l) {
  __builtin_amdgcn_global_load_lds(
      (const __attribute__((address_space(1))) unsigned int*)g,
      (__attribute__((address_space(3))) unsigned int*)l,
      16, 0, 0);
}

// ---- fused prep: weight cvt (y<4), hidden cvt (y<8), rope tables (y==8) ----
struct PrepArgs {
  const float* w0; const float* w1; const float* w2; const float* w3;
  bf16* b0; bf16* b1; bf16* b2; bf16* b3;
  const float* hs; bf16* hb;
  const float* rot; float* ct; float* st;
};
__global__ void k_prep(PrepArgs a) {
  const int y = blockIdx.y;
  const int i = blockIdx.x * 256 + threadIdx.x;
  if (y < 4) {
    const float* s = (y == 0) ? a.w0 : (y == 1) ? a.w1 : (y == 2) ? a.w2 : a.w3;
    bf16* d = (y == 0) ? a.b0 : (y == 1) ? a.b1 : (y == 2) ? a.b2 : a.b3;
    float4 v = reinterpret_cast<const float4*>(s)[i];
    bf16x4 o = { (bf16)v.x, (bf16)v.y, (bf16)v.z, (bf16)v.w };
    *reinterpret_cast<bf16x4*>(d + (size_t)i * 4) = o;
  } else if (y < 8) {
    size_t off = (size_t)(y - 4) * (NM * NE / 16);   // quarter of hidden, in float4s
    float4 v = reinterpret_cast<const float4*>(a.hs)[off + i];
    bf16x4 o = { (bf16)v.x, (bf16)v.y, (bf16)v.z, (bf16)v.w };
    *reinterpret_cast<bf16x4*>(a.hb + (off + i) * 4) = o;
  } else {
    if (i < NS * NROT) {
      float v = a.rot[i];
      a.ct[i] = cosf(v);
      a.st[i] = sinf(v);
    }
  }
}

// =====================================================================
// A-shared fused QKV projection, 16 waves (1024 threads): one block =
// 128 A-rows x 128 n-cols for Q, K, AND V. 4 waves/SIMD for latency hiding.
// Waves: 4M x 4N, wave tile 32x32 per output. BK=64 double-buffered.
// Per K-tile: stage(t+1) -> vmcnt(4)+barrier (publish t; t+1's 4 loads fly)
//   -> per-kk {2 A + 6 B ds_reads, 12 MFMA setprio} -> lgkmcnt(0)+barrier.
// LDS: A 2x16KB + 3x W 2x16KB = 128KB.  (Measured: 44 us, Occ 36%.)
// =====================================================================
__global__ __launch_bounds__(1024) void k_proj(
    const bf16* __restrict__ A, const bf16* __restrict__ Wq, const bf16* __restrict__ Wk,
    const bf16* __restrict__ Wv, bf16* __restrict__ Oq, bf16* __restrict__ Ok,
    bf16* __restrict__ vt, const float* __restrict__ ct, const float* __restrict__ st)
{
  __shared__ bf16 lA[2 * 128 * 64];
  __shared__ bf16 lW[3][2 * 128 * 64];
  const int m0 = blockIdx.x * 128, n0 = blockIdx.y * 128;
  const int tid = threadIdx.x;
  const int wave = tid >> 6, lane = tid & 63;   // wave 0..15
  const int wm = wave >> 2, wn = wave & 3;      // 4 m-quarters x 4 n-quarters
  const int fr = lane & 15, kg = lane >> 4;
  const int lrow8 = lane >> 3, lslot = lane & 7;

  // wave stages chunk `wave` of each of A, W0, W1, W2 (4 loads)
  auto stage = [&](int kt, int c) {
    const int chunk = wave;                     // 0..15
    const int row = (chunk << 3) + lrow8;       // 0..127
    const int slot = lslot ^ (row & 7);
    const size_t rowA = (size_t)(m0 + row) * NE + kt + slot * 8;
    const size_t rowW = (size_t)(n0 + row) * NE + kt + slot * 8;
    gload_lds16(A  + rowA, (char*)lA    + c * 16384 + chunk * 1024);
    gload_lds16(Wq + rowW, (char*)lW[0] + c * 16384 + chunk * 1024);
    gload_lds16(Wk + rowW, (char*)lW[1] + c * 16384 + chunk * 1024);
    gload_lds16(Wv + rowW, (char*)lW[2] + c * 16384 + chunk * 1024);
  };

  stage(0, 0);

  constexpr int NT = NE / 64;   // 16
  f32x4 aq[2][2] = {}, ak[2][2] = {}, av[2][2] = {};

  for (int t = 0; t < NT; ++t) {
    const int c = t & 1;
    // stage t+1 into c^1 (all waves' t-1 reads of c^1 retired at E(t-1))
    if (t + 1 < NT) stage((t + 1) * 64, c ^ 1);

    // publish tile t: wait own 4 stage-loads of t; t+1's 4 stay in flight
    if (t + 1 < NT)
      asm volatile("s_waitcnt vmcnt(4)\n\ts_barrier" ::: "memory");
    else
      asm volatile("s_waitcnt vmcnt(0)\n\ts_barrier" ::: "memory");

    const bf16* cA = lA + c * 8192;
    const bf16* cQ = lW[0] + c * 8192;
    const bf16* cK = lW[1] + c * 8192;
    const bf16* cV = lW[2] + c * 8192;

#pragma unroll
    for (int kk = 0; kk < 2; ++kk) {
      bf16x8 af[2], bq[2], bk[2], bv[2];
#pragma unroll
      for (int p = 0; p < 2; ++p) {
        int ra = wm * 32 + p * 16 + fr;
        af[p] = *reinterpret_cast<const bf16x8*>(
            cA + ra * 64 + (((kg + 4 * kk) ^ (ra & 7)) << 3));
      }
#pragma unroll
      for (int j = 0; j < 2; ++j) {
        int rb = wn * 32 + j * 16 + fr;
        int off = rb * 64 + (((kg + 4 * kk) ^ (rb & 7)) << 3);
        bq[j] = *reinterpret_cast<const bf16x8*>(cQ + off);
        bk[j] = *reinterpret_cast<const bf16x8*>(cK + off);
        bv[j] = *reinterpret_cast<const bf16x8*>(cV + off);
      }
      __builtin_amdgcn_s_setprio(1);
#pragma unroll
      for (int p = 0; p < 2; ++p)
#pragma unroll
        for (int j = 0; j < 2; ++j) {
          aq[p][j] = __builtin_amdgcn_mfma_f32_16x16x32_bf16(af[p], bq[j], aq[p][j], 0, 0, 0);
          ak[p][j] = __builtin_amdgcn_mfma_f32_16x16x32_bf16(af[p], bk[j], ak[p][j], 0, 0, 0);
          av[j][p] = __builtin_amdgcn_mfma_f32_16x16x32_bf16(bv[j], af[p], av[j][p], 0, 0, 0);
        }
      __builtin_amdgcn_s_setprio(0);
    }

    // end of K-tile: retire all reads of buf c before t+2 overwrites it
    asm volatile("s_waitcnt lgkmcnt(0)\n\ts_barrier" ::: "memory");
  }

  // ---- epilogues ----
  const int nb = n0 + wn * 32;                  // wave's first n-col (32-aligned)
  const bool ropeHalf = ((nb & 63) == 0);       // cols 0-31 of a head
  const float qscale = 0.125f * 1.44269504f;

  // Q and K: row = m0 + wm*32 + p*16 + kg*4 + r, cols nb+fr / nb+16+fr
#pragma unroll
  for (int p = 0; p < 2; ++p)
#pragma unroll
    for (int r = 0; r < 4; ++r) {
      int gm = m0 + wm * 32 + p * 16 + kg * 4 + r;
      int s = gm & (NS - 1);
      size_t rb = (size_t)gm * NE + nb;
      float q0v = aq[p][0][r] * qscale, q1v = aq[p][1][r] * qscale;
      float k0v = ak[p][0][r],          k1v = ak[p][1][r];
      if (ropeHalf) {
        float c0 = ct[s * NROT + fr],      sn0 = st[s * NROT + fr];
        float c1 = ct[s * NROT + 16 + fr], sn1 = st[s * NROT + 16 + fr];
        Oq[rb + fr]      = (bf16)(q0v * c0 - q1v * sn0);
        Oq[rb + 16 + fr] = (bf16)(q1v * c1 + q0v * sn1);
        Ok[rb + fr]      = (bf16)(k0v * c0 - k1v * sn0);
        Ok[rb + 16 + fr] = (bf16)(k1v * c1 + k0v * sn1);
      } else {
        Oq[rb + fr]      = (bf16)q0v;
        Oq[rb + 16 + fr] = (bf16)q1v;
        Ok[rb + fr]      = (bf16)k0v;
        Ok[rb + 16 + fr] = (bf16)k1v;
      }
    }

  // V transposed: vt[bh][d][s]; wave covers e-cols nb..nb+31 (one half-head)
  {
    const int b = m0 >> 10;
    const int h = nb >> 6;
    const int eb = nb & 63;                     // 0 or 32
    bf16* vtb = vt + ((size_t)(b * 16 + h)) * ND * NS;
#pragma unroll
    for (int p = 0; p < 2; ++p) {
      int sl = (m0 & (NS - 1)) + wm * 32 + p * 16 + fr;
#pragma unroll
      for (int r = 0; r < 4; ++r) {
        int dbase = kg * 4 + r;                 // 0..15
        float x0 = av[0][p][r];                 // e = eb + dbase
        float x1 = av[1][p][r];                 // e = eb + 16 + dbase
        if (eb == 0) {
          float c0 = ct[sl * NROT + dbase],      sn0 = st[sl * NROT + dbase];
          float c1 = ct[sl * NROT + 16 + dbase], sn1 = st[sl * NROT + 16 + dbase];
          vtb[(size_t)(dbase)      * NS + sl] = (bf16)(x0 * c0 - x1 * sn0);
          vtb[(size_t)(16 + dbase) * NS + sl] = (bf16)(x1 * c1 + x0 * sn1);
        } else {
          vtb[(size_t)(32 + dbase) * NS + sl] = (bf16)x0;
          vtb[(size_t)(48 + dbase) * NS + sl] = (bf16)x1;
        }
      }
    }
  }
}

// =====================================================================
// Output projection + bias, 16 waves (R19 structure, single GEMM):
// 128x128 tile, BK=64 dbuf, counted vmcnt(2) publish, 4 waves/SIMD.
// Per K-tile per wave: 2 stage loads, 8 ds_read_b128, 8 MFMA (setprio).
// =====================================================================
__global__ __launch_bounds__(1024) void k_gemm_o(
    const bf16* __restrict__ A, const bf16* __restrict__ W, float* __restrict__ Og,
    const float* __restrict__ bias)
{
  __shared__ bf16 lA[2 * 128 * 64];
  __shared__ bf16 lB[2 * 128 * 64];
  const int m0 = blockIdx.x * 128, n0 = blockIdx.y * 128;
  const int tid = threadIdx.x;
  const int wave = tid >> 6, lane = tid & 63;   // wave 0..15
  const int wm = wave >> 2, wn = wave & 3;      // 4 m-quarters x 4 n-quarters
  const int fr = lane & 15, kg = lane >> 4;
  const int lrow8 = lane >> 3, lslot = lane & 7;

  auto stage = [&](int kt, int c) {
    const int chunk = wave;                     // 0..15
    const int row = (chunk << 3) + lrow8;       // 0..127
    const int slot = lslot ^ (row & 7);
    gload_lds16(A + (size_t)(m0 + row) * NE + kt + slot * 8,
                (char*)lA + c * 16384 + chunk * 1024);
    gload_lds16(W + (size_t)(n0 + row) * NE + kt + slot * 8,
                (char*)lB + c * 16384 + chunk * 1024);
  };

  stage(0, 0);

  constexpr int NT = NE / 64;   // 16
  f32x4 acc[2][2] = {};

  for (int t = 0; t < NT; ++t) {
    const int c = t & 1;
    if (t + 1 < NT) stage((t + 1) * 64, c ^ 1);

    if (t + 1 < NT)
      asm volatile("s_waitcnt vmcnt(2)\n\ts_barrier" ::: "memory");
    else
      asm volatile("s_waitcnt vmcnt(0)\n\ts_barrier" ::: "memory");

    const bf16* cA = lA + c * 8192;
    const bf16* cB = lB + c * 8192;

#pragma unroll
    for (int kk = 0; kk < 2; ++kk) {
      bf16x8 af[2], bw[2];
#pragma unroll
      for (int p = 0; p < 2; ++p) {
        int ra = wm * 32 + p * 16 + fr;
        af[p] = *reinterpret_cast<const bf16x8*>(
            cA + ra * 64 + (((kg + 4 * kk) ^ (ra & 7)) << 3));
      }
#pragma unroll
      for (int j = 0; j < 2; ++j) {
        int rb = wn * 32 + j * 16 + fr;
        bw[j] = *reinterpret_cast<const bf16x8*>(
            cB + rb * 64 + (((kg + 4 * kk) ^ (rb & 7)) << 3));
      }
      __builtin_amdgcn_s_setprio(1);
#pragma unroll
      for (int p = 0; p < 2; ++p)
#pragma unroll
        for (int j = 0; j < 2; ++j)
          acc[p][j] = __builtin_amdgcn_mfma_f32_16x16x32_bf16(af[p], bw[j], acc[p][j], 0, 0, 0);
      __builtin_amdgcn_s_setprio(0);
    }

    asm volatile("s_waitcnt lgkmcnt(0)\n\ts_barrier" ::: "memory");
  }

  // epilogue: f32 + bias
#pragma unroll
  for (int p = 0; p < 2; ++p)
#pragma unroll
    for (int j = 0; j < 2; ++j) {
      int gc = n0 + wn * 32 + j * 16 + fr;
      float bv = bias[gc];
#pragma unroll
      for (int r = 0; r < 4; ++r) {
        int gm = m0 + wm * 32 + p * 16 + kg * 4 + r;
        Og[(size_t)gm * NE + gc] = acc[p][j][r] + bv;
      }
    }
}

// ---- causal flash attention: swapped-QK^T in-lane softmax, ONE barrier/tile ----
__global__ __launch_bounds__(256) void k_attn(
    const bf16* __restrict__ Q, const bf16* __restrict__ K,
    const bf16* __restrict__ VT, bf16* __restrict__ O)
{
  __shared__ bf16 lK[2][64 * 64];
  __shared__ bf16 lVT[2][64 * 64];
  __shared__ bf16 lP[4][16 * 68];
  const int tid = threadIdx.x;
  const int wave = tid >> 6, lane = tid & 63;
  const int fr = lane & 15, kg = lane >> 4;

  const int qt = 15 - (blockIdx.y >> 3);          // descending: long blocks first
  const int bh = blockIdx.x | ((blockIdx.y & 7) << 3);
  const int b = bh >> 4, h = bh & 15;
  const int nt = qt + 1;
  const bf16* Qb  = Q + (size_t)b * NS * NE + h * 64;
  const bf16* Kb  = K + (size_t)b * NS * NE + h * 64;
  const bf16* VTb = VT + (size_t)bh * ND * NS;
  bf16* Ob = O + (size_t)b * NS * NE + h * 64;

  const int qrow0 = qt * 64 + wave * 16;

  bf16x8 qf[2];
#pragma unroll
  for (int kk = 0; kk < 2; ++kk)
    qf[kk] = *reinterpret_cast<const bf16x8*>(
        Qb + (size_t)(qrow0 + fr) * NE + kk * 32 + kg * 8);

  const int srow = lane >> 3;
  const int sslot = (lane & 7) ^ srow;
  const int r0 = wave * 8 + srow;
  const int r1 = (wave + 4) * 8 + srow;
  const bf16* kA0 = Kb + (size_t)r0 * NE + sslot * 8;
  const bf16* kA1 = Kb + (size_t)r1 * NE + sslot * 8;
  const bf16* vA0 = VTb + (size_t)r0 * NS + sslot * 8;
  const bf16* vA1 = VTb + (size_t)r1 * NS + sslot * 8;
  char* ldsKa[2] = { (char*)lK[0] + wave * 1024, (char*)lK[1] + wave * 1024 };
  char* ldsKb[2] = { (char*)lK[0] + (wave + 4) * 1024, (char*)lK[1] + (wave + 4) * 1024 };
  char* ldsVa[2] = { (char*)lVT[0] + wave * 1024, (char*)lVT[1] + wave * 1024 };
  char* ldsVb[2] = { (char*)lVT[0] + (wave + 4) * 1024, (char*)lVT[1] + (wave + 4) * 1024 };

  float m_ = -3.0e38f, l_ = 0.f;
  f32x4 oacc[4] = {};

  gload_lds16(kA0, ldsKa[0]);
  gload_lds16(kA1, ldsKb[0]);
  gload_lds16(vA0, ldsVa[0]);
  gload_lds16(vA1, ldsVb[0]);
  __syncthreads();

  for (int t = 0; t < nt; ++t) {
    const int c = t & 1;
    if (t + 1 < nt) {
      gload_lds16(kA0 + (size_t)(t + 1) * 64 * NE, ldsKa[c ^ 1]);
      gload_lds16(kA1 + (size_t)(t + 1) * 64 * NE, ldsKb[c ^ 1]);
      gload_lds16(vA0 + (t + 1) * 64, ldsVa[c ^ 1]);
      gload_lds16(vA1 + (t + 1) * 64, ldsVb[c ^ 1]);
    }

    const bf16* lKc = lK[c];
    f32x4 sacc[4] = {};
    __builtin_amdgcn_s_setprio(1);
#pragma unroll
    for (int kk = 0; kk < 2; ++kk)
#pragma unroll
      for (int j = 0; j < 4; ++j) {
        int rc = j * 16 + fr;
        bf16x8 kf = *reinterpret_cast<const bf16x8*>(
            lKc + rc * 64 + (((kg + 4 * kk) ^ (rc & 7)) << 3));
        sacc[j] = __builtin_amdgcn_mfma_f32_16x16x32_bf16(kf, qf[kk], sacc[j], 0, 0, 0);
      }
    __builtin_amdgcn_s_setprio(0);

    if (t == qt) {
      const int ql = wave * 16 + fr;
#pragma unroll
      for (int j = 0; j < 4; ++j)
#pragma unroll
        for (int r = 0; r < 4; ++r)
          if (16 * j + 4 * kg + r > ql) sacc[j][r] = -3.0e38f;
    }

    float m4 = fmaxf(fmaxf(fmaxf(sacc[0][0], sacc[0][1]), fmaxf(sacc[0][2], sacc[0][3])),
                     fmaxf(fmaxf(sacc[1][0], sacc[1][1]), fmaxf(sacc[1][2], sacc[1][3])));
    m4 = fmaxf(m4, fmaxf(fmaxf(fmaxf(sacc[2][0], sacc[2][1]), fmaxf(sacc[2][2], sacc[2][3])),
                         fmaxf(fmaxf(sacc[3][0], sacc[3][1]), fmaxf(sacc[3][2], sacc[3][3]))));
    m4 = fmaxf(m4, __shfl_xor(m4, 16));
    m4 = fmaxf(m4, __shfl_xor(m4, 32));

    if (!__all(m4 - m_ <= 8.0f)) {
      float nm = fmaxf(m_, m4);
      float corr = exp2f(m_ - nm);
      m_ = nm;
      l_ *= corr;
#pragma unroll
      for (int r = 0; r < 4; ++r) {
        float cr = __shfl(corr, kg * 4 + r);
#pragma unroll
        for (int df = 0; df < 4; ++df) oacc[df][r] *= cr;
      }
    }

    float ps = 0.f;
#pragma unroll
    for (int j = 0; j < 4; ++j) {
      float p0 = exp2f(sacc[j][0] - m_);
      float p1 = exp2f(sacc[j][1] - m_);
      float p2 = exp2f(sacc[j][2] - m_);
      float p3 = exp2f(sacc[j][3] - m_);
      ps += (p0 + p1) + (p2 + p3);
      bf16x4 pp = { (bf16)p0, (bf16)p1, (bf16)p2, (bf16)p3 };
      *reinterpret_cast<bf16x4*>(&lP[wave][fr * 68 + j * 16 + kg * 4]) = pp;
    }
    ps += __shfl_xor(ps, 16);
    ps += __shfl_xor(ps, 32);
    l_ += ps;

    const bf16* lVc = lVT[c];
    __builtin_amdgcn_s_setprio(1);
#pragma unroll
    for (int ks = 0; ks < 2; ++ks) {
      bf16x8 pf = *reinterpret_cast<const bf16x8*>(&lP[wave][fr * 68 + ks * 32 + kg * 8]);
#pragma unroll
      for (int df = 0; df < 4; ++df) {
        int d = df * 16 + fr;
        bf16x8 vf = *reinterpret_cast<const bf16x8*>(
            lVc + d * 64 + (((kg + 4 * ks) ^ (d & 7)) << 3));
        oacc[df] = __builtin_amdgcn_mfma_f32_16x16x32_bf16(pf, vf, oacc[df], 0, 0, 0);
      }
    }
    __builtin_amdgcn_s_setprio(0);

    if (t + 1 < nt)
      asm volatile("s_waitcnt vmcnt(0)\n\ts_barrier" ::: "memory");
  }

  float linv[4];
#pragma unroll
  for (int r = 0; r < 4; ++r) linv[r] = 1.0f / __shfl(l_, kg * 4 + r);
#pragma unroll
  for (int df = 0; df < 4; ++df)
#pragma unroll
    for (int r = 0; r < 4; ++r)
      Ob[(size_t)(qrow0 + kg * 4 + r) * NE + df * 16 + fr] = (bf16)(oacc[df][r] * linv[r]);
}

extern "C" void kernel_launch(void* const* d_in, const int* in_sizes, int n_in,
                              void* d_out, int out_size, void* d_ws, size_t ws_size,
                              hipStream_t stream) {
  const float* hs  = (const float*)d_in[0];
  const float* rot = (const float*)d_in[1];
  const float* qw  = (const float*)d_in[2];
  const float* kw  = (const float*)d_in[3];
  const float* vw  = (const float*)d_in[4];
  const float* ow  = (const float*)d_in[5];
  const float* obb = (const float*)d_in[6];
  float* out = (float*)d_out;

  char* ws = (char*)d_ws;
  size_t off = 0;
  bf16* hb  = (bf16*)(ws + off); off += (size_t)NM * NE * 2;
  bf16* wqb = (bf16*)(ws + off); off += (size_t)NE * NE * 2;
  bf16* wkb = (bf16*)(ws + off); off += (size_t)NE * NE * 2;
  bf16* wvb = (bf16*)(ws + off); off += (size_t)NE * NE * 2;
  bf16* wob = (bf16*)(ws + off); off += (size_t)NE * NE * 2;
  bf16* qb  = (bf16*)(ws + off); off += (size_t)NM * NE * 2;
  bf16* kb  = (bf16*)(ws + off); off += (size_t)NM * NE * 2;
  bf16* vt  = (bf16*)(ws + off); off += (size_t)NM * NE * 2;   // [bh][d][s]
  float* ct = (float*)(ws + off); off += (size_t)NS * NROT * 4;
  float* st = (float*)(ws + off); off += (size_t)NS * NROT * 4;
  bf16* aob = hb;   // hidden bf16 is dead after projections

  // fused prep (one dispatch): 4 weight-cvt slices, 4 hidden-cvt slices, tables
  PrepArgs pa = { qw, kw, vw, ow, wqb, wkb, wvb, wob, hs, hb, rot, ct, st };
  k_prep<<<dim3(NE * NE / 4 / 256, 9), dim3(256), 0, stream>>>(pa);

  // A-shared fused QKV projections + rope (256 blocks x 1024 threads)
  k_proj<<<dim3(NM / 128, NE / 128), dim3(1024), 0, stream>>>(
      hb, wqb, wkb, wvb, qb, kb, vt, ct, st);

  // causal flash attention (single-tile blocks, qt-descending, 1024 blocks)
  k_attn<<<dim3(8, 128), dim3(256), 0, stream>>>(qb, kb, vt, aob);

  // output projection + bias (16-wave counted-vmcnt core)
  k_gemm_o<<<dim3(NM / 128, NE / 128), dim3(1024), 0, stream>>>(aob, wob, out, obb);

  (void)in_sizes; (void)n_in; (void)out_size; (void)ws_size;
}

// Round 23
// 93.003 us; speedup vs baseline: 1.0133x; 1.0133x over previous
//
#include <hip/hip_runtime.h>
#include <hip/hip_bf16.h>

typedef __bf16 bf16;
typedef __attribute__((ext_vector_type(2))) __bf16 bf16x2;
typedef __attribute__((ext_vector_type(4))) __bf16 bf16x4;
typedef __attribute__((ext_vector_type(8))) __bf16 bf16x8;
typedef __attribute__((ext_vector_type(4))) float f32x4;

#define NB 4
#define NS 1024
#define NE 1024
#define NH 16
#define ND 64
#define NROT 32
#define NM (NB*NS)   // 4096 rows

// ---- async global->LDS, 16B per lane, wave-uniform LDS base ----
__device__ __forceinline__ void gload_lds16(const bf16* g, void* l) {
  __builtin_amdgcn_global_load_lds(
      (const __attribute__((address_space(1))) unsigned int*)g,
      (__attribute__((address_space(3))) unsigned int*)l,
      16, 0, 0);
}

// ---- fused prep: weight cvt (y<4), hidden cvt (y<8), rope tables (y==8) ----
struct PrepArgs {
  const float* w0; const float* w1; const float* w2; const float* w3;
  bf16* b0; bf16* b1; bf16* b2; bf16* b3;
  const float* hs; bf16* hb;
  const float* rot; float* ct; float* st;
};
__global__ void k_prep(PrepArgs a) {
  const int y = blockIdx.y;
  const int i = blockIdx.x * 256 + threadIdx.x;
  if (y < 4) {
    const float* s = (y == 0) ? a.w0 : (y == 1) ? a.w1 : (y == 2) ? a.w2 : a.w3;
    bf16* d = (y == 0) ? a.b0 : (y == 1) ? a.b1 : (y == 2) ? a.b2 : a.b3;
    float4 v = reinterpret_cast<const float4*>(s)[i];
    bf16x4 o = { (bf16)v.x, (bf16)v.y, (bf16)v.z, (bf16)v.w };
    *reinterpret_cast<bf16x4*>(d + (size_t)i * 4) = o;
  } else if (y < 8) {
    size_t off = (size_t)(y - 4) * (NM * NE / 16);   // quarter of hidden, in float4s
    float4 v = reinterpret_cast<const float4*>(a.hs)[off + i];
    bf16x4 o = { (bf16)v.x, (bf16)v.y, (bf16)v.z, (bf16)v.w };
    *reinterpret_cast<bf16x4*>(a.hb + (off + i) * 4) = o;
  } else {
    if (i < NS * NROT) {
      float v = a.rot[i];
      a.ct[i] = cosf(v);
      a.st[i] = sinf(v);
    }
  }
}

// =====================================================================
// A-shared fused QKV projection, 16 waves (1024 threads): one block =
// 128 A-rows x 128 n-cols for Q, K, AND V. 4 waves/SIMD for latency hiding.
// Waves: 4M x 4N, wave tile 32x32 per output. BK=64 double-buffered.
// Per K-tile: stage(t+1) -> vmcnt(4)+barrier (publish t; t+1's 4 loads fly)
//   -> per-kk {2 A + 6 B ds_reads, 12 MFMA setprio} -> lgkmcnt(0)+barrier.
// LDS: A 2x16KB + 3x W 2x16KB = 128KB.  (Measured: 44 us, Occ 36%.)
// =====================================================================
__global__ __launch_bounds__(1024) void k_proj(
    const bf16* __restrict__ A, const bf16* __restrict__ Wq, const bf16* __restrict__ Wk,
    const bf16* __restrict__ Wv, bf16* __restrict__ Oq, bf16* __restrict__ Ok,
    bf16* __restrict__ vt, const float* __restrict__ ct, const float* __restrict__ st)
{
  __shared__ bf16 lA[2 * 128 * 64];
  __shared__ bf16 lW[3][2 * 128 * 64];
  const int m0 = blockIdx.x * 128, n0 = blockIdx.y * 128;
  const int tid = threadIdx.x;
  const int wave = tid >> 6, lane = tid & 63;   // wave 0..15
  const int wm = wave >> 2, wn = wave & 3;      // 4 m-quarters x 4 n-quarters
  const int fr = lane & 15, kg = lane >> 4;
  const int lrow8 = lane >> 3, lslot = lane & 7;

  // wave stages chunk `wave` of each of A, W0, W1, W2 (4 loads)
  auto stage = [&](int kt, int c) {
    const int chunk = wave;                     // 0..15
    const int row = (chunk << 3) + lrow8;       // 0..127
    const int slot = lslot ^ (row & 7);
    const size_t rowA = (size_t)(m0 + row) * NE + kt + slot * 8;
    const size_t rowW = (size_t)(n0 + row) * NE + kt + slot * 8;
    gload_lds16(A  + rowA, (char*)lA    + c * 16384 + chunk * 1024);
    gload_lds16(Wq + rowW, (char*)lW[0] + c * 16384 + chunk * 1024);
    gload_lds16(Wk + rowW, (char*)lW[1] + c * 16384 + chunk * 1024);
    gload_lds16(Wv + rowW, (char*)lW[2] + c * 16384 + chunk * 1024);
  };

  stage(0, 0);

  constexpr int NT = NE / 64;   // 16
  f32x4 aq[2][2] = {}, ak[2][2] = {}, av[2][2] = {};

  for (int t = 0; t < NT; ++t) {
    const int c = t & 1;
    // stage t+1 into c^1 (all waves' t-1 reads of c^1 retired at E(t-1))
    if (t + 1 < NT) stage((t + 1) * 64, c ^ 1);

    // publish tile t: wait own 4 stage-loads of t; t+1's 4 stay in flight
    if (t + 1 < NT)
      asm volatile("s_waitcnt vmcnt(4)\n\ts_barrier" ::: "memory");
    else
      asm volatile("s_waitcnt vmcnt(0)\n\ts_barrier" ::: "memory");

    const bf16* cA = lA + c * 8192;
    const bf16* cQ = lW[0] + c * 8192;
    const bf16* cK = lW[1] + c * 8192;
    const bf16* cV = lW[2] + c * 8192;

#pragma unroll
    for (int kk = 0; kk < 2; ++kk) {
      bf16x8 af[2], bq[2], bk[2], bv[2];
#pragma unroll
      for (int p = 0; p < 2; ++p) {
        int ra = wm * 32 + p * 16 + fr;
        af[p] = *reinterpret_cast<const bf16x8*>(
            cA + ra * 64 + (((kg + 4 * kk) ^ (ra & 7)) << 3));
      }
#pragma unroll
      for (int j = 0; j < 2; ++j) {
        int rb = wn * 32 + j * 16 + fr;
        int off = rb * 64 + (((kg + 4 * kk) ^ (rb & 7)) << 3);
        bq[j] = *reinterpret_cast<const bf16x8*>(cQ + off);
        bk[j] = *reinterpret_cast<const bf16x8*>(cK + off);
        bv[j] = *reinterpret_cast<const bf16x8*>(cV + off);
      }
      __builtin_amdgcn_s_setprio(1);
#pragma unroll
      for (int p = 0; p < 2; ++p)
#pragma unroll
        for (int j = 0; j < 2; ++j) {
          aq[p][j] = __builtin_amdgcn_mfma_f32_16x16x32_bf16(af[p], bq[j], aq[p][j], 0, 0, 0);
          ak[p][j] = __builtin_amdgcn_mfma_f32_16x16x32_bf16(af[p], bk[j], ak[p][j], 0, 0, 0);
          av[j][p] = __builtin_amdgcn_mfma_f32_16x16x32_bf16(bv[j], af[p], av[j][p], 0, 0, 0);
        }
      __builtin_amdgcn_s_setprio(0);
    }

    // end of K-tile: retire all reads of buf c before t+2 overwrites it
    asm volatile("s_waitcnt lgkmcnt(0)\n\ts_barrier" ::: "memory");
  }

  // ---- epilogues ----
  const int nb = n0 + wn * 32;                  // wave's first n-col (32-aligned)
  const bool ropeHalf = ((nb & 63) == 0);       // cols 0-31 of a head
  const float qscale = 0.125f * 1.44269504f;

  // Q and K: row = m0 + wm*32 + p*16 + kg*4 + r, cols nb+fr / nb+16+fr
#pragma unroll
  for (int p = 0; p < 2; ++p)
#pragma unroll
    for (int r = 0; r < 4; ++r) {
      int gm = m0 + wm * 32 + p * 16 + kg * 4 + r;
      int s = gm & (NS - 1);
      size_t rb = (size_t)gm * NE + nb;
      float q0v = aq[p][0][r] * qscale, q1v = aq[p][1][r] * qscale;
      float k0v = ak[p][0][r],          k1v = ak[p][1][r];
      if (ropeHalf) {
        float c0 = ct[s * NROT + fr],      sn0 = st[s * NROT + fr];
        float c1 = ct[s * NROT + 16 + fr], sn1 = st[s * NROT + 16 + fr];
        Oq[rb + fr]      = (bf16)(q0v * c0 - q1v * sn0);
        Oq[rb + 16 + fr] = (bf16)(q1v * c1 + q0v * sn1);
        Ok[rb + fr]      = (bf16)(k0v * c0 - k1v * sn0);
        Ok[rb + 16 + fr] = (bf16)(k1v * c1 + k0v * sn1);
      } else {
        Oq[rb + fr]      = (bf16)q0v;
        Oq[rb + 16 + fr] = (bf16)q1v;
        Ok[rb + fr]      = (bf16)k0v;
        Ok[rb + 16 + fr] = (bf16)k1v;
      }
    }

  // V transposed: vt[bh][d][s]; wave covers e-cols nb..nb+31 (one half-head)
  {
    const int b = m0 >> 10;
    const int h = nb >> 6;
    const int eb = nb & 63;                     // 0 or 32
    bf16* vtb = vt + ((size_t)(b * 16 + h)) * ND * NS;
#pragma unroll
    for (int p = 0; p < 2; ++p) {
      int sl = (m0 & (NS - 1)) + wm * 32 + p * 16 + fr;
#pragma unroll
      for (int r = 0; r < 4; ++r) {
        int dbase = kg * 4 + r;                 // 0..15
        float x0 = av[0][p][r];                 // e = eb + dbase
        float x1 = av[1][p][r];                 // e = eb + 16 + dbase
        if (eb == 0) {
          float c0 = ct[sl * NROT + dbase],      sn0 = st[sl * NROT + dbase];
          float c1 = ct[sl * NROT + 16 + dbase], sn1 = st[sl * NROT + 16 + dbase];
          vtb[(size_t)(dbase)      * NS + sl] = (bf16)(x0 * c0 - x1 * sn0);
          vtb[(size_t)(16 + dbase) * NS + sl] = (bf16)(x1 * c1 + x0 * sn1);
        } else {
          vtb[(size_t)(32 + dbase) * NS + sl] = (bf16)x0;
          vtb[(size_t)(48 + dbase) * NS + sl] = (bf16)x1;
        }
      }
    }
  }
}

// ---- output projection + bias: simple single-buffered core (best-total cfg) ----
__global__ __launch_bounds__(256) void k_gemm_o(
    const bf16* __restrict__ A, const bf16* __restrict__ W, float* __restrict__ Og,
    const float* __restrict__ bias)
{
  __shared__ bf16 lA[64 * 64];
  __shared__ bf16 lB[128 * 64];
  const int m0 = blockIdx.x * 64, n0 = blockIdx.y * 128;
  const int tid = threadIdx.x;
  const int wave = tid >> 6, lane = tid & 63;
  const int wm = wave >> 1, wn = wave & 1;
  const int fr = lane & 15, kg = lane >> 4;
  const int lrow8 = lane >> 3, lslot = lane & 7;

  f32x4 acc[2][4] = {};

  for (int kt = 0; kt < NE; kt += 64) {
#pragma unroll
    for (int i = 0; i < 2; ++i) {
      int chunk = i * 4 + wave;
      int row = (chunk << 3) + lrow8;
      int slot = lslot ^ (row & 7);
      gload_lds16(A + (size_t)(m0 + row) * NE + kt + slot * 8, (char*)lA + chunk * 1024);
    }
#pragma unroll
    for (int i = 0; i < 4; ++i) {
      int chunk = i * 4 + wave;
      int row = (chunk << 3) + lrow8;
      int slot = lslot ^ (row & 7);
      gload_lds16(W + (size_t)(n0 + row) * NE + kt + slot * 8, (char*)lB + chunk * 1024);
    }
    __syncthreads();
#pragma unroll
    for (int kk = 0; kk < 2; ++kk) {
      bf16x8 af[2], bfr[4];
#pragma unroll
      for (int i = 0; i < 2; ++i) {
        int ra = wm * 32 + i * 16 + fr;
        af[i] = *reinterpret_cast<const bf16x8*>(lA + ra * 64 + (((kg + 4 * kk) ^ (ra & 7)) << 3));
      }
#pragma unroll
      for (int j = 0; j < 4; ++j) {
        int rb = wn * 64 + j * 16 + fr;
        bfr[j] = *reinterpret_cast<const bf16x8*>(lB + rb * 64 + (((kg + 4 * kk) ^ (rb & 7)) << 3));
      }
#pragma unroll
      for (int i = 0; i < 2; ++i)
#pragma unroll
        for (int j = 0; j < 4; ++j)
          acc[i][j] = __builtin_amdgcn_mfma_f32_16x16x32_bf16(af[i], bfr[j], acc[i][j], 0, 0, 0);
    }
    __syncthreads();
  }

#pragma unroll
  for (int i = 0; i < 2; ++i)
#pragma unroll
    for (int j = 0; j < 4; ++j) {
      int gc = n0 + wn * 64 + j * 16 + fr;
      float bv = bias[gc];
#pragma unroll
      for (int r = 0; r < 4; ++r) {
        int gm = m0 + wm * 32 + i * 16 + kg * 4 + r;
        Og[(size_t)gm * NE + gc] = acc[i][j][r] + bv;
      }
    }
}

// ---- causal flash attention: swapped-QK^T in-lane softmax, ONE barrier/tile ----
__global__ __launch_bounds__(256) void k_attn(
    const bf16* __restrict__ Q, const bf16* __restrict__ K,
    const bf16* __restrict__ VT, bf16* __restrict__ O)
{
  __shared__ bf16 lK[2][64 * 64];
  __shared__ bf16 lVT[2][64 * 64];
  __shared__ bf16 lP[4][16 * 68];
  const int tid = threadIdx.x;
  const int wave = tid >> 6, lane = tid & 63;
  const int fr = lane & 15, kg = lane >> 4;

  const int qt = 15 - (blockIdx.y >> 3);          // descending: long blocks first
  const int bh = blockIdx.x | ((blockIdx.y & 7) << 3);
  const int b = bh >> 4, h = bh & 15;
  const int nt = qt + 1;
  const bf16* Qb  = Q + (size_t)b * NS * NE + h * 64;
  const bf16* Kb  = K + (size_t)b * NS * NE + h * 64;
  const bf16* VTb = VT + (size_t)bh * ND * NS;
  bf16* Ob = O + (size_t)b * NS * NE + h * 64;

  const int qrow0 = qt * 64 + wave * 16;

  bf16x8 qf[2];
#pragma unroll
  for (int kk = 0; kk < 2; ++kk)
    qf[kk] = *reinterpret_cast<const bf16x8*>(
        Qb + (size_t)(qrow0 + fr) * NE + kk * 32 + kg * 8);

  const int srow = lane >> 3;
  const int sslot = (lane & 7) ^ srow;
  const int r0 = wave * 8 + srow;
  const int r1 = (wave + 4) * 8 + srow;
  const bf16* kA0 = Kb + (size_t)r0 * NE + sslot * 8;
  const bf16* kA1 = Kb + (size_t)r1 * NE + sslot * 8;
  const bf16* vA0 = VTb + (size_t)r0 * NS + sslot * 8;
  const bf16* vA1 = VTb + (size_t)r1 * NS + sslot * 8;
  char* ldsKa[2] = { (char*)lK[0] + wave * 1024, (char*)lK[1] + wave * 1024 };
  char* ldsKb[2] = { (char*)lK[0] + (wave + 4) * 1024, (char*)lK[1] + (wave + 4) * 1024 };
  char* ldsVa[2] = { (char*)lVT[0] + wave * 1024, (char*)lVT[1] + wave * 1024 };
  char* ldsVb[2] = { (char*)lVT[0] + (wave + 4) * 1024, (char*)lVT[1] + (wave + 4) * 1024 };

  float m_ = -3.0e38f, l_ = 0.f;
  f32x4 oacc[4] = {};

  gload_lds16(kA0, ldsKa[0]);
  gload_lds16(kA1, ldsKb[0]);
  gload_lds16(vA0, ldsVa[0]);
  gload_lds16(vA1, ldsVb[0]);
  __syncthreads();

  for (int t = 0; t < nt; ++t) {
    const int c = t & 1;
    if (t + 1 < nt) {
      gload_lds16(kA0 + (size_t)(t + 1) * 64 * NE, ldsKa[c ^ 1]);
      gload_lds16(kA1 + (size_t)(t + 1) * 64 * NE, ldsKb[c ^ 1]);
      gload_lds16(vA0 + (t + 1) * 64, ldsVa[c ^ 1]);
      gload_lds16(vA1 + (t + 1) * 64, ldsVb[c ^ 1]);
    }

    const bf16* lKc = lK[c];
    f32x4 sacc[4] = {};
    __builtin_amdgcn_s_setprio(1);
#pragma unroll
    for (int kk = 0; kk < 2; ++kk)
#pragma unroll
      for (int j = 0; j < 4; ++j) {
        int rc = j * 16 + fr;
        bf16x8 kf = *reinterpret_cast<const bf16x8*>(
            lKc + rc * 64 + (((kg + 4 * kk) ^ (rc & 7)) << 3));
        sacc[j] = __builtin_amdgcn_mfma_f32_16x16x32_bf16(kf, qf[kk], sacc[j], 0, 0, 0);
      }
    __builtin_amdgcn_s_setprio(0);

    if (t == qt) {
      const int ql = wave * 16 + fr;
#pragma unroll
      for (int j = 0; j < 4; ++j)
#pragma unroll
        for (int r = 0; r < 4; ++r)
          if (16 * j + 4 * kg + r > ql) sacc[j][r] = -3.0e38f;
    }

    float m4 = fmaxf(fmaxf(fmaxf(sacc[0][0], sacc[0][1]), fmaxf(sacc[0][2], sacc[0][3])),
                     fmaxf(fmaxf(sacc[1][0], sacc[1][1]), fmaxf(sacc[1][2], sacc[1][3])));
    m4 = fmaxf(m4, fmaxf(fmaxf(fmaxf(sacc[2][0], sacc[2][1]), fmaxf(sacc[2][2], sacc[2][3])),
                         fmaxf(fmaxf(sacc[3][0], sacc[3][1]), fmaxf(sacc[3][2], sacc[3][3]))));
    m4 = fmaxf(m4, __shfl_xor(m4, 16));
    m4 = fmaxf(m4, __shfl_xor(m4, 32));

    if (!__all(m4 - m_ <= 8.0f)) {
      float nm = fmaxf(m_, m4);
      float corr = exp2f(m_ - nm);
      m_ = nm;
      l_ *= corr;
#pragma unroll
      for (int r = 0; r < 4; ++r) {
        float cr = __shfl(corr, kg * 4 + r);
#pragma unroll
        for (int df = 0; df < 4; ++df) oacc[df][r] *= cr;
      }
    }

    float ps = 0.f;
#pragma unroll
    for (int j = 0; j < 4; ++j) {
      float p0 = exp2f(sacc[j][0] - m_);
      float p1 = exp2f(sacc[j][1] - m_);
      float p2 = exp2f(sacc[j][2] - m_);
      float p3 = exp2f(sacc[j][3] - m_);
      ps += (p0 + p1) + (p2 + p3);
      bf16x4 pp = { (bf16)p0, (bf16)p1, (bf16)p2, (bf16)p3 };
      *reinterpret_cast<bf16x4*>(&lP[wave][fr * 68 + j * 16 + kg * 4]) = pp;
    }
    ps += __shfl_xor(ps, 16);
    ps += __shfl_xor(ps, 32);
    l_ += ps;

    const bf16* lVc = lVT[c];
    __builtin_amdgcn_s_setprio(1);
#pragma unroll
    for (int ks = 0; ks < 2; ++ks) {
      bf16x8 pf = *reinterpret_cast<const bf16x8*>(&lP[wave][fr * 68 + ks * 32 + kg * 8]);
#pragma unroll
      for (int df = 0; df < 4; ++df) {
        int d = df * 16 + fr;
        bf16x8 vf = *reinterpret_cast<const bf16x8*>(
            lVc + d * 64 + (((kg + 4 * ks) ^ (d & 7)) << 3));
        oacc[df] = __builtin_amdgcn_mfma_f32_16x16x32_bf16(pf, vf, oacc[df], 0, 0, 0);
      }
    }
    __builtin_amdgcn_s_setprio(0);

    if (t + 1 < nt)
      asm volatile("s_waitcnt vmcnt(0)\n\ts_barrier" ::: "memory");
  }

  float linv[4];
#pragma unroll
  for (int r = 0; r < 4; ++r) linv[r] = 1.0f / __shfl(l_, kg * 4 + r);
#pragma unroll
  for (int df = 0; df < 4; ++df)
#pragma unroll
    for (int r = 0; r < 4; ++r)
      Ob[(size_t)(qrow0 + kg * 4 + r) * NE + df * 16 + fr] = (bf16)(oacc[df][r] * linv[r]);
}

extern "C" void kernel_launch(void* const* d_in, const int* in_sizes, int n_in,
                              void* d_out, int out_size, void* d_ws, size_t ws_size,
                              hipStream_t stream) {
  const float* hs  = (const float*)d_in[0];
  const float* rot = (const float*)d_in[1];
  const float* qw  = (const float*)d_in[2];
  const float* kw  = (const float*)d_in[3];
  const float* vw  = (const float*)d_in[4];
  const float* ow  = (const float*)d_in[5];
  const float* obb = (const float*)d_in[6];
  float* out = (float*)d_out;

  char* ws = (char*)d_ws;
  size_t off = 0;
  bf16* hb  = (bf16*)(ws + off); off += (size_t)NM * NE * 2;
  bf16* wqb = (bf16*)(ws + off); off += (size_t)NE * NE * 2;
  bf16* wkb = (bf16*)(ws + off); off += (size_t)NE * NE * 2;
  bf16* wvb = (bf16*)(ws + off); off += (size_t)NE * NE * 2;
  bf16* wob = (bf16*)(ws + off); off += (size_t)NE * NE * 2;
  bf16* qb  = (bf16*)(ws + off); off += (size_t)NM * NE * 2;
  bf16* kb  = (bf16*)(ws + off); off += (size_t)NM * NE * 2;
  bf16* vt  = (bf16*)(ws + off); off += (size_t)NM * NE * 2;   // [bh][d][s]
  float* ct = (float*)(ws + off); off += (size_t)NS * NROT * 4;
  float* st = (float*)(ws + off); off += (size_t)NS * NROT * 4;
  bf16* aob = hb;   // hidden bf16 is dead after projections

  // fused prep (one dispatch): 4 weight-cvt slices, 4 hidden-cvt slices, tables
  PrepArgs pa = { qw, kw, vw, ow, wqb, wkb, wvb, wob, hs, hb, rot, ct, st };
  k_prep<<<dim3(NE * NE / 4 / 256, 9), dim3(256), 0, stream>>>(pa);

  // A-shared fused QKV projections + rope (256 blocks x 1024 threads)
  k_proj<<<dim3(NM / 128, NE / 128), dim3(1024), 0, stream>>>(
      hb, wqb, wkb, wvb, qb, kb, vt, ct, st);

  // causal flash attention (single-tile blocks, qt-descending, 1024 blocks)
  k_attn<<<dim3(8, 128), dim3(256), 0, stream>>>(qb, kb, vt, aob);

  // output projection + bias (simple single-buffered core)
  k_gemm_o<<<dim3(NM / 64, NE / 128), dim3(256), 0, stream>>>(aob, wob, out, obb);

  (void)in_sizes; (void)n_in; (void)out_size; (void)ws_size;
}